// Round 10
// baseline (623.041 us; speedup 1.0000x reference)
//
#include <hip/hip_runtime.h>
#include <stdint.h>

// ---- filter / neuron constants (double, matching the Python reference) ----
#define EMD 0.8824969025845955      // exp(-1/8)
#define ESD 0.6065306597126334      // exp(-1/2)
#define A1C ((float)(EMD + ESD))                    // y[t-1] coeff
#define A2C ((float)(-(EMD * ESD)))                 // y[t-2] coeff
#define BC  ((float)((8.0 / 6.0) * (EMD - ESD)))    // x[t] coeff (ETA=8/6)
#define EMF ((float)EMD)                            // reset decay

// B=64, T=300. Layers: 300 -> 500 -> 200 -> 500 -> 300.
//
// Exactness contract (absmax 0.0, rounds 1-9): reference currents are a
// SEQUENTIAL ascending-i fp32 fold of W[o,i]*s[i]; spikes are exactly 0/1.
// Skipping s==0 terms is bitwise-neutral; adds happen in ascending-i order.
// Pad indices read an all-zero LDS row: acc + (+0.0) is bitwise-identity.

// ---------------------------------------------------------------------------
// Generic batched transpose: src [Bt][R][C] -> dst [Bt][C][R]
// ---------------------------------------------------------------------------
__global__ __launch_bounds__(256) void transpose_rc(
    const float* __restrict__ src, float* __restrict__ dst, int R, int C)
{
    __shared__ float tile[32][33];
    const int c0 = blockIdx.x * 32;
    const int r0 = blockIdx.y * 32;
    const int b  = blockIdx.z;
    const float* S = src + (size_t)b * R * C;
    float* D = dst + (size_t)b * R * C;
    const int tx = threadIdx.x;      // 0..31
    const int ty = threadIdx.y;      // 0..7
#pragma unroll
    for (int s = 0; s < 4; s++) {
        const int r = r0 + ty + 8 * s;
        const int c = c0 + tx;
        if (r < R && c < C) tile[ty + 8 * s][tx] = S[(size_t)r * C + c];
    }
    __syncthreads();
#pragma unroll
    for (int s = 0; s < 4; s++) {
        const int c = c0 + ty + 8 * s;
        const int r = r0 + tx;
        if (c < C && r < R) D[(size_t)c * R + r] = tile[tx][ty + 8 * s];
    }
}

// ---------------------------------------------------------------------------
// build_idx (lane-parallel): per (b,t,kchunk of 32) pack ascending set-bit
// indices (+1) into 8 u32 (4/word, zero-padded) + group count ceil(n/4) u8.
// One wave per (b,t); each iteration covers 2 chunks (64 k's). Active lane
// scatters byte (pos+1) at its prefix rank into wave-private LDS; lanes 0-15
// read the u32 words back. No serial ctz chain.
// cnt8 layout: [kc][b][320]; pk32 layout: [kc][b][300][8].
// ---------------------------------------------------------------------------
__global__ __launch_bounds__(256) void build_idx(
    const float* __restrict__ Sp, uint8_t* __restrict__ cnt8,
    uint32_t* __restrict__ pk32, int K, int nkc)
{
    __shared__ uint32_t stage32[4][16];       // 64 B per wave, wave-private
    const int tid  = threadIdx.x;
    const int wv   = tid >> 6;
    const int lane = tid & 63;
    const int pos  = lane & 31;
    const int half = lane >> 5;               // which chunk of the pair
    const int b    = blockIdx.y;
    const int t    = blockIdx.x * 4 + wv;     // grid.x = 75 -> t < 300
    const float* row = Sp + ((size_t)b * 300 + t) * K;

    // preload all spike values (up to 16 chunks = 8 iters of 64)
    float sv[8];
#pragma unroll
    for (int i = 0; i < 8; i++) {
        const int k = i * 64 + lane;
        sv[i] = (i * 2 < nkc && k < K) ? row[k] : 0.0f;
    }

    volatile uint8_t*  sb  = (volatile uint8_t*)&stage32[wv][0];
    volatile uint32_t* sw  = (volatile uint32_t*)&stage32[wv][0];

    const int nit = (nkc + 1) >> 1;
    for (int i = 0; i < nit; i++) {
        const unsigned long long bal = __ballot(sv[i] != 0.0f);
        const uint32_t m32 = (uint32_t)(bal >> (half * 32));
        const int rank = __popc(m32 & ((1u << pos) - 1u));
        sb[lane] = 0;                                       // zero 64 B
        if (sv[i] != 0.0f) sb[half * 32 + rank] = (uint8_t)(pos + 1);
        // wave-private region + per-wave DS ordering -> no barrier needed
        if (lane < 16) {
            const int h   = lane >> 3;
            const int w   = lane & 7;
            const int kcc = i * 2 + h;
            if (kcc < nkc)
                pk32[(((size_t)kcc * 64 + b) * 300 + t) * 8 + w] =
                    sw[h * 8 + w];
        }
        if (pos == 0) {                                     // lanes 0 and 32
            const int kcc = i * 2 + half;
            if (kcc < nkc)
                cnt8[((size_t)kcc * 64 + b) * 320 + t] =
                    (uint8_t)((__popc(m32) + 3) >> 2);
        }
    }
}

// ---------------------------------------------------------------------------
// spmm_idx: C[b,t,o] = sum_{i in idx(b,t)} Wt[i,o]   (time-major, [B,T,O])
// Block: 256 thr (4 waves). Lane covers 4 o's (float4 / ds_read_b128).
// o-chunk 256, t-chunk 4*RPW. K chunked at 32 rows in LDS (+ zero row 0 for
// pads); weights register-prefetched one chunk ahead. Packed index words are
// hoisted into SGPRs via two s_load_dwordx4 per (u,kc) BEFORE the group
// processing, which is guard-unrolled over 8 groups (uniform SCC branches) —
// round 9 kept a serial in-loop s_load on the ds_read critical path.
// ---------------------------------------------------------------------------
#define KG  32
#define OCN 256

template <int RPW>
__global__ __launch_bounds__(256) void spmm_idx(
    const float* __restrict__ Wt, float* __restrict__ C,
    const uint8_t* __restrict__ cnt8, const uint32_t* __restrict__ pk32,
    int K, int O, int nkc)
{
    __shared__ float Wls[(KG + 1) * OCN];   // row 0 = zeros; 33 KB
    const int tid  = threadIdx.x;
    const int lane = tid & 63;
    const int wvs  = __builtin_amdgcn_readfirstlane(tid >> 6);  // wave id, scalar
    const int oc   = blockIdx.x * OCN;
    const int t0   = blockIdx.y * (4 * RPW);
    const int b    = blockIdx.z;

    Wls[tid] = 0.0f;                        // zero row 0 (256 floats)

    const int scol  = lane * 4;             // 0..252
    const int srow0 = tid >> 6;             // 0..3

    float4 wpf[8];
#define LOADW(kc)                                                              \
    {                                                                          \
        const int kb_ = (kc) * KG;                                             \
        _Pragma("unroll")                                                      \
        for (int r = 0; r < 8; r++) {                                          \
            const int k = kb_ + srow0 + r * 4;                                 \
            float4 w = make_float4(0.f, 0.f, 0.f, 0.f);                        \
            if (k < K && oc + scol + 3 < O)                                    \
                w = *reinterpret_cast<const float4*>(&Wt[(size_t)k * O + oc + scol]); \
            wpf[r] = w;                                                        \
        }                                                                      \
    }
#define STOREW()                                                               \
    {                                                                          \
        _Pragma("unroll")                                                      \
        for (int r = 0; r < 8; r++)                                            \
            *reinterpret_cast<float4*>(&Wls[(size_t)(srow0 + r * 4 + 1) * OCN + scol]) = wpf[r]; \
    }

// one group of 4 packed byte-indices (word in SGPR), ascending order
#define GRP(gi, word)                                                          \
    if (ng > (gi)) {                                                           \
        const uint32_t pw = (word);                                            \
        const int f0 = (int)((pw      ) & 0xffu) << 8;                         \
        const int f1 = (int)((pw >> 8 ) & 0xffu) << 8;                         \
        const int f2 = (int)((pw >> 16) & 0xffu) << 8;                         \
        const int f3 = (int)((pw >> 24)        ) << 8;                         \
        const float4 w0 = *reinterpret_cast<const float4*>(lrow + f0);         \
        const float4 w1 = *reinterpret_cast<const float4*>(lrow + f1);         \
        const float4 w2 = *reinterpret_cast<const float4*>(lrow + f2);         \
        const float4 w3 = *reinterpret_cast<const float4*>(lrow + f3);         \
        a.x += w0.x; a.y += w0.y; a.z += w0.z; a.w += w0.w;                    \
        a.x += w1.x; a.y += w1.y; a.z += w1.z; a.w += w1.w;                    \
        a.x += w2.x; a.y += w2.y; a.z += w2.z; a.w += w2.w;                    \
        a.x += w3.x; a.y += w3.y; a.z += w3.z; a.w += w3.w;                    \
    }

    float4 acc[RPW];
#pragma unroll
    for (int u = 0; u < RPW; u++) acc[u] = make_float4(0.f, 0.f, 0.f, 0.f);

    LOADW(0)
    STOREW()
    __syncthreads();

    const float* lrow = Wls + lane * 4;     // + idx*256 floats selects the row

    for (int kc = 0; kc < nkc; kc++) {
        if (kc + 1 < nkc) LOADW(kc + 1)     // overlaps the index loops below
        const uint32_t* c32 =
            (const uint32_t*)(cnt8 + ((size_t)kc * 64 + b) * 320 + t0);
        const uint4* pb = (const uint4*)(pk32 + ((size_t)kc * 64 + b) * 300 * 8);
#pragma unroll
        for (int u = 0; u < RPW; u++) {
            const int ts = t0 + u * 4 + wvs;
            const int tsafe = (ts < 299) ? ts : 299;      // clamp tail (guarded)
            int ng = (int)((c32[u] >> (wvs * 8)) & 0xffu);
            if (ts >= 300) ng = 0;
            // hoisted: both packed words in SGPRs before any LDS read
            const uint4 pw0 = pb[(size_t)tsafe * 2];
            const uint4 pw1 = pb[(size_t)tsafe * 2 + 1];
            float4 a = acc[u];
            GRP(0, pw0.x) GRP(1, pw0.y) GRP(2, pw0.z) GRP(3, pw0.w)
            GRP(4, pw1.x) GRP(5, pw1.y) GRP(6, pw1.z) GRP(7, pw1.w)
            acc[u] = a;
        }
        if (kc + 1 < nkc) {
            __syncthreads();
            STOREW()
            __syncthreads();
        }
    }

    float* Cb = C + (size_t)b * 300 * O;
#pragma unroll
    for (int u = 0; u < RPW; u++) {
        const int t = t0 + u * 4 + wvs;
        const int o = oc + lane * 4;
        if (t < 300 && o + 3 < O)           // O%4==0 -> all-or-nothing
            *reinterpret_cast<float4*>(&Cb[(size_t)t * O + o]) = acc[u];
    }
}

// ---------------------------------------------------------------------------
// LIF in time-major layout, in-place: C[b,t,o] currents -> spikes.
// One thread per (b,o); strided column walk, 8-deep unrolled prefetch ring.
// ---------------------------------------------------------------------------
#define LIF_STEP_S(xval, sval)                                                 \
    {                                                                          \
        const float y = A1 * y1 + A2 * y2 + Bc * (xval); y2 = y1; y1 = y;      \
        const float v = y + bi + r;                                            \
        sval = (v >= 1.0f) ? 1.0f : 0.0f;                                      \
        r = r * EMF - sval;                                                    \
    }

__global__ __launch_bounds__(64) void lif_t(
    float* __restrict__ C, const float* __restrict__ bias,
    const float* __restrict__ a1p, const float* __restrict__ a2p,
    const float* __restrict__ bp, int O)
{
    const int o = blockIdx.x * 64 + threadIdx.x;
    const int b = blockIdx.y;
    if (o >= O) return;
    const float A1 = a1p[0], A2 = a2p[0], Bc = bp[0];
    const float bi = bias[o];
    float* col = C + (size_t)b * 300 * O + o;

    float pf[8];
#pragma unroll
    for (int u = 0; u < 8; u++) pf[u] = col[(size_t)u * O];

    float y1 = 0.f, y2 = 0.f, r = 0.f;
    for (int blk = 0; blk < 37; blk++) {       // t = 0..295
#pragma unroll
        for (int u = 0; u < 8; u++) {
            const int t = blk * 8 + u;
            const float x = pf[u];
            if (t + 8 < 300) pf[u] = col[(size_t)(t + 8) * O];
            float s;
            LIF_STEP_S(x, s)
            col[(size_t)t * O] = s;
        }
    }
#pragma unroll
    for (int u = 0; u < 4; u++) {              // t = 296..299
        const float x = pf[u];
        float s;
        LIF_STEP_S(x, s)
        col[(size_t)(296 + u) * O] = s;
    }
}

// ---------------------------------------------------------------------------
// Layer-4 LIF + fixed output dual-exp IIR. C: currents->spikes (in place),
// F: filtered output. Both [B,T,O], O=300.
// ---------------------------------------------------------------------------
__global__ __launch_bounds__(64) void lif4_t(
    float* __restrict__ C, float* __restrict__ F,
    const float* __restrict__ bias,
    const float* __restrict__ a1p, const float* __restrict__ a2p,
    const float* __restrict__ bp, int O)
{
    const int o = blockIdx.x * 64 + threadIdx.x;
    const int b = blockIdx.y;
    if (o >= O) return;
    const float A1 = a1p[0], A2 = a2p[0], Bc = bp[0];
    const float bi = bias[o];
    float* col  = C + (size_t)b * 300 * O + o;
    float* fcol = F + (size_t)b * 300 * O + o;

    float pf[8];
#pragma unroll
    for (int u = 0; u < 8; u++) pf[u] = col[(size_t)u * O];

    float y1 = 0.f, y2 = 0.f, r = 0.f;
    float z1 = 0.f, z2 = 0.f;
    for (int blk = 0; blk < 37; blk++) {
#pragma unroll
        for (int u = 0; u < 8; u++) {
            const int t = blk * 8 + u;
            const float x = pf[u];
            if (t + 8 < 300) pf[u] = col[(size_t)(t + 8) * O];
            float s;
            LIF_STEP_S(x, s)
            const float z = A1C * z1 + A2C * z2 + BC * s; z2 = z1; z1 = z;
            col[(size_t)t * O]  = s;
            fcol[(size_t)t * O] = z;
        }
    }
#pragma unroll
    for (int u = 0; u < 4; u++) {
        const int t = 296 + u;
        const float x = pf[u];
        float s;
        LIF_STEP_S(x, s)
        const float z = A1C * z1 + A2C * z2 + BC * s; z2 = z1; z1 = z;
        col[(size_t)t * O]  = s;
        fcol[(size_t)t * O] = z;
    }
}

// ---------------------------------------------------------------------------
extern "C" void kernel_launch(void* const* d_in, const int* in_sizes, int n_in,
                              void* d_out, int out_size, void* d_ws, size_t ws_size,
                              hipStream_t stream)
{
    const float* inputs = (const float*)d_in[0];           // [64,300,300] binary
    const float* a1_1 = (const float*)d_in[1];
    const float* a2_1 = (const float*)d_in[2];
    const float* b_1  = (const float*)d_in[3];
    const float* W1   = (const float*)d_in[4];             // [500,300]
    const float* bias1= (const float*)d_in[5];
    const float* a1_2 = (const float*)d_in[6];
    const float* a2_2 = (const float*)d_in[7];
    const float* b_2  = (const float*)d_in[8];
    const float* W2   = (const float*)d_in[9];             // [200,500]
    const float* bias2= (const float*)d_in[10];
    const float* a1_3 = (const float*)d_in[11];
    const float* a2_3 = (const float*)d_in[12];
    const float* b_3  = (const float*)d_in[13];
    const float* W3   = (const float*)d_in[14];            // [500,200]
    const float* bias3= (const float*)d_in[15];
    const float* a1_4 = (const float*)d_in[16];
    const float* a2_4 = (const float*)d_in[17];
    const float* b_4  = (const float*)d_in[18];
    const float* W4   = (const float*)d_in[19];            // [300,500]
    const float* bias4= (const float*)d_in[20];

    const int B = 64;

    // Workspace (53.76 MB): c1 = 9.6M floats, c2 = 3.84M floats.
    float* ws = (float*)d_ws;
    float* c1 = ws;                 // [B,T,500]; later filt_tmp [B,T,300]
    float* c2 = ws + 9600000;       // [B,T,200]

    // d_out regions double as scratch until the final transposes:
    // reg1 [0..5.76M): Wt1..4 (500K fl) + idx scratch, later final s4 [B,O,T]
    // reg2 [5.76M..11.52M): inputT / c4 / s4_tmp [B,T,300], later final filt
    float* out = (float*)d_out;
    float* reg1 = out;
    float* reg2 = out + 5760000;
    float* Wt1 = reg1;              // [300,500] = 150000
    float* Wt2 = reg1 + 150000;     // [500,200] = 100000
    float* Wt3 = reg1 + 250000;     // [200,500] = 100000
    float* Wt4 = reg1 + 350000;     // [500,300] = 150000
    uint8_t*  cnt8 = (uint8_t*)(reg1 + 500000);   // 16*64*320 B = 328 KB
    uint32_t* pk32 = (uint32_t*)(reg1 + 582000);  // 16*64*300*8 u32 = 9.8 MB
                                                  // ends at reg1+3,039,600

    const dim3 tb(32, 8);

    // Weight transposes W[O,K] -> Wt[K,O]
    transpose_rc<<<dim3(10, 16, 1), tb, 0, stream>>>(W1, Wt1, 500, 300);
    transpose_rc<<<dim3(16,  7, 1), tb, 0, stream>>>(W2, Wt2, 200, 500);
    transpose_rc<<<dim3( 7, 16, 1), tb, 0, stream>>>(W3, Wt3, 500, 200);
    transpose_rc<<<dim3(16, 10, 1), tb, 0, stream>>>(W4, Wt4, 300, 500);
    // Input spikes [B,IN,T] -> [B,T,IN]
    transpose_rc<<<dim3(10, 10, B), tb, 0, stream>>>(inputs, reg2, 300, 300);

    // Layer 1: 300 -> 500  (nkc = 10)
    build_idx<<<dim3(75, B), 256, 0, stream>>>(reg2, cnt8, pk32, 300, 10);
    spmm_idx<8><<<dim3(2, 10, B), 256, 0, stream>>>(Wt1, c1, cnt8, pk32, 300, 500, 10);
    lif_t<<<dim3(8, B), 64, 0, stream>>>(c1, bias1, a1_1, a2_1, b_1, 500);
    // Layer 2: 500 -> 200  (nkc = 16; 1 o-chunk -> RPW=4 for more blocks)
    build_idx<<<dim3(75, B), 256, 0, stream>>>(c1, cnt8, pk32, 500, 16);
    spmm_idx<4><<<dim3(1, 19, B), 256, 0, stream>>>(Wt2, c2, cnt8, pk32, 500, 200, 16);
    lif_t<<<dim3(4, B), 64, 0, stream>>>(c2, bias2, a1_2, a2_2, b_2, 200);
    // Layer 3: 200 -> 500  (nkc = 7)
    build_idx<<<dim3(75, B), 256, 0, stream>>>(c2, cnt8, pk32, 200, 7);
    spmm_idx<8><<<dim3(2, 10, B), 256, 0, stream>>>(Wt3, c1, cnt8, pk32, 200, 500, 7);
    lif_t<<<dim3(8, B), 64, 0, stream>>>(c1, bias3, a1_3, a2_3, b_3, 500);
    // Layer 4: 500 -> 300 into reg2 (inputT dead); fused LIF + output filter
    build_idx<<<dim3(75, B), 256, 0, stream>>>(c1, cnt8, pk32, 500, 16);
    spmm_idx<8><<<dim3(2, 10, B), 256, 0, stream>>>(Wt4, reg2, cnt8, pk32, 500, 300, 16);
    lif4_t<<<dim3(5, B), 64, 0, stream>>>(reg2, c1, bias4, a1_4, a2_4, b_4, 300);

    // Final transposes [B,T,O] -> [B,O,T]: s4 (overwrites Wt/idx), then filt.
    transpose_rc<<<dim3(10, 10, B), tb, 0, stream>>>(reg2, reg1, 300, 300);
    transpose_rc<<<dim3(10, 10, B), tb, 0, stream>>>(c1, reg2, 300, 300);
}

// Round 11
// 547.460 us; speedup vs baseline: 1.1381x; 1.1381x over previous
//
#include <hip/hip_runtime.h>
#include <stdint.h>

// ---- filter / neuron constants (double, matching the Python reference) ----
#define EMD 0.8824969025845955      // exp(-1/8)
#define ESD 0.6065306597126334      // exp(-1/2)
#define A1C ((float)(EMD + ESD))                    // y[t-1] coeff
#define A2C ((float)(-(EMD * ESD)))                 // y[t-2] coeff
#define BC  ((float)((8.0 / 6.0) * (EMD - ESD)))    // x[t] coeff (ETA=8/6)
#define EMF ((float)EMD)                            // reset decay

// B=64, T=300. Layers: 300 -> 500 -> 200 -> 500 -> 300.
//
// Exactness contract (absmax 0.0, rounds 1-10): reference currents are a
// SEQUENTIAL ascending-i fp32 fold of W[o,i]*s[i]; spikes are exactly 0/1.
// Skipping s==0 terms is bitwise-neutral; adds happen in ascending-i order.
// Zero-selected words / pad bytes read the all-zero LDS row: acc + (+0.0)
// is bitwise-identity (acc is never -0: starts +0, +0+(+/-0)=+0 in RN).

// ---------------------------------------------------------------------------
// Generic batched transpose: src [Bt][R][C] -> dst [Bt][C][R]
// ---------------------------------------------------------------------------
__global__ __launch_bounds__(256) void transpose_rc(
    const float* __restrict__ src, float* __restrict__ dst, int R, int C)
{
    __shared__ float tile[32][33];
    const int c0 = blockIdx.x * 32;
    const int r0 = blockIdx.y * 32;
    const int b  = blockIdx.z;
    const float* S = src + (size_t)b * R * C;
    float* D = dst + (size_t)b * R * C;
    const int tx = threadIdx.x;      // 0..31
    const int ty = threadIdx.y;      // 0..7
#pragma unroll
    for (int s = 0; s < 4; s++) {
        const int r = r0 + ty + 8 * s;
        const int c = c0 + tx;
        if (r < R && c < C) tile[ty + 8 * s][tx] = S[(size_t)r * C + c];
    }
    __syncthreads();
#pragma unroll
    for (int s = 0; s < 4; s++) {
        const int c = c0 + ty + 8 * s;
        const int r = r0 + tx;
        if (c < C && r < R) D[(size_t)c * R + r] = tile[tx][ty + 8 * s];
    }
}

// ---------------------------------------------------------------------------
// build_idx (lane-parallel): per (b,t,kchunk of 32) pack ascending set-bit
// indices (+1) into 8 u32 (4/word, zero-padded) + group count ceil(n/4) u8.
// One wave per (b,t); each iteration covers 2 chunks (64 k's). Active lane
// scatters byte (pos+1) at its prefix rank into wave-private LDS; lanes 0-15
// read the u32 words back. No serial ctz chain.
// cnt8 layout: [kc][b][320]; pk32 layout: [kc][b][300][8].
// ---------------------------------------------------------------------------
__global__ __launch_bounds__(256) void build_idx(
    const float* __restrict__ Sp, uint8_t* __restrict__ cnt8,
    uint32_t* __restrict__ pk32, int K, int nkc)
{
    __shared__ uint32_t stage32[4][16];       // 64 B per wave, wave-private
    const int tid  = threadIdx.x;
    const int wv   = tid >> 6;
    const int lane = tid & 63;
    const int pos  = lane & 31;
    const int half = lane >> 5;               // which chunk of the pair
    const int b    = blockIdx.y;
    const int t    = blockIdx.x * 4 + wv;     // grid.x = 75 -> t < 300
    const float* row = Sp + ((size_t)b * 300 + t) * K;

    // preload all spike values (up to 16 chunks = 8 iters of 64)
    float sv[8];
#pragma unroll
    for (int i = 0; i < 8; i++) {
        const int k = i * 64 + lane;
        sv[i] = (i * 2 < nkc && k < K) ? row[k] : 0.0f;
    }

    volatile uint8_t*  sb  = (volatile uint8_t*)&stage32[wv][0];
    volatile uint32_t* sw  = (volatile uint32_t*)&stage32[wv][0];

    const int nit = (nkc + 1) >> 1;
    for (int i = 0; i < nit; i++) {
        const unsigned long long bal = __ballot(sv[i] != 0.0f);
        const uint32_t m32 = (uint32_t)(bal >> (half * 32));
        const int rank = __popc(m32 & ((1u << pos) - 1u));
        sb[lane] = 0;                                       // zero 64 B
        if (sv[i] != 0.0f) sb[half * 32 + rank] = (uint8_t)(pos + 1);
        // wave-private region + per-wave DS ordering -> no barrier needed
        if (lane < 16) {
            const int h   = lane >> 3;
            const int w   = lane & 7;
            const int kcc = i * 2 + h;
            if (kcc < nkc)
                pk32[(((size_t)kcc * 64 + b) * 300 + t) * 8 + w] =
                    sw[h * 8 + w];
        }
        if (pos == 0) {                                     // lanes 0 and 32
            const int kcc = i * 2 + half;
            if (kcc < nkc)
                cnt8[((size_t)kcc * 64 + b) * 320 + t] =
                    (uint8_t)((__popc(m32) + 3) >> 2);
        }
    }
}

// ---------------------------------------------------------------------------
// spmm_idx: C[b,t,o] = sum_{i in idx(b,t)} Wt[i,o]   (time-major, [B,T,O])
// Block: 256 thr (4 waves). Lane covers 4 o's (float4 / ds_read_b128).
// o-chunk 256, t-chunk 4*RPW. K chunked at 32 rows in LDS (+ zero row 0 for
// pads); weights register-prefetched one chunk ahead.
// Inner loop: PAIR of t-rows in lockstep per group, guarded only on the
// pair-max count; per-row word is scalar-SELECTED to 0 (-> zero row, exact
// identity adds). Each taken group = ONE basic block with 8 independent
// ds_read_b128 + 32 adds. Rounds 8-10 had per-row guards -> one tiny basic
// block per group -> no cross-row ILP, serial ~100cyc/group, VALUBusy 19%.
// ---------------------------------------------------------------------------
#define KG  32
#define OCN 256

template <int RPW>
__global__ __launch_bounds__(256, 4) void spmm_idx(
    const float* __restrict__ Wt, float* __restrict__ C,
    const uint8_t* __restrict__ cnt8, const uint32_t* __restrict__ pk32,
    int K, int O, int nkc)
{
    __shared__ float Wls[(KG + 1) * OCN];   // row 0 = zeros; 33 KB
    const int tid  = threadIdx.x;
    const int lane = tid & 63;
    const int wvs  = __builtin_amdgcn_readfirstlane(tid >> 6);  // wave id, scalar
    const int oc   = blockIdx.x * OCN;
    const int t0   = blockIdx.y * (4 * RPW);
    const int b    = blockIdx.z;

    Wls[tid] = 0.0f;                        // zero row 0 (256 floats)

    const int scol  = lane * 4;             // 0..252
    const int srow0 = tid >> 6;             // 0..3

    float4 wpf[8];
#define LOADW(kc)                                                              \
    {                                                                          \
        const int kb_ = (kc) * KG;                                             \
        _Pragma("unroll")                                                      \
        for (int r = 0; r < 8; r++) {                                          \
            const int k = kb_ + srow0 + r * 4;                                 \
            float4 w = make_float4(0.f, 0.f, 0.f, 0.f);                        \
            if (k < K && oc + scol + 3 < O)                                    \
                w = *reinterpret_cast<const float4*>(&Wt[(size_t)k * O + oc + scol]); \
            wpf[r] = w;                                                        \
        }                                                                      \
    }
#define STOREW()                                                               \
    {                                                                          \
        _Pragma("unroll")                                                      \
        for (int r = 0; r < 8; r++)                                            \
            *reinterpret_cast<float4*>(&Wls[(size_t)(srow0 + r * 4 + 1) * OCN + scol]) = wpf[r]; \
    }

// One group for the row PAIR: guarded on pair-max only; per-row word
// scalar-selected to 0 when that row is done (zero row -> identity adds).
// 8 independent ds_read_b128 in one basic block.
#define GRP2(gi, wa, wb)                                                       \
    if (ngm > (gi)) {                                                          \
        const uint32_t pa = (ng0 > (gi)) ? (wa) : 0u;                          \
        const uint32_t pq = (ng1 > (gi)) ? (wb) : 0u;                          \
        const int fa0 = (int)((pa      ) & 0xffu) << 8;                        \
        const int fa1 = (int)((pa >> 8 ) & 0xffu) << 8;                        \
        const int fa2 = (int)((pa >> 16) & 0xffu) << 8;                        \
        const int fa3 = (int)((pa >> 24)        ) << 8;                        \
        const int fb0 = (int)((pq      ) & 0xffu) << 8;                        \
        const int fb1 = (int)((pq >> 8 ) & 0xffu) << 8;                        \
        const int fb2 = (int)((pq >> 16) & 0xffu) << 8;                        \
        const int fb3 = (int)((pq >> 24)        ) << 8;                        \
        const float4 wa0 = *reinterpret_cast<const float4*>(lrow + fa0);       \
        const float4 wa1 = *reinterpret_cast<const float4*>(lrow + fa1);       \
        const float4 wa2 = *reinterpret_cast<const float4*>(lrow + fa2);       \
        const float4 wa3 = *reinterpret_cast<const float4*>(lrow + fa3);       \
        const float4 wb0 = *reinterpret_cast<const float4*>(lrow + fb0);       \
        const float4 wb1 = *reinterpret_cast<const float4*>(lrow + fb1);       \
        const float4 wb2 = *reinterpret_cast<const float4*>(lrow + fb2);       \
        const float4 wb3 = *reinterpret_cast<const float4*>(lrow + fb3);       \
        a0.x += wa0.x; a0.y += wa0.y; a0.z += wa0.z; a0.w += wa0.w;            \
        a0.x += wa1.x; a0.y += wa1.y; a0.z += wa1.z; a0.w += wa1.w;            \
        a0.x += wa2.x; a0.y += wa2.y; a0.z += wa2.z; a0.w += wa2.w;            \
        a0.x += wa3.x; a0.y += wa3.y; a0.z += wa3.z; a0.w += wa3.w;            \
        a1.x += wb0.x; a1.y += wb0.y; a1.z += wb0.z; a1.w += wb0.w;            \
        a1.x += wb1.x; a1.y += wb1.y; a1.z += wb1.z; a1.w += wb1.w;            \
        a1.x += wb2.x; a1.y += wb2.y; a1.z += wb2.z; a1.w += wb2.w;            \
        a1.x += wb3.x; a1.y += wb3.y; a1.z += wb3.z; a1.w += wb3.w;            \
    }

    float4 acc[RPW];
#pragma unroll
    for (int u = 0; u < RPW; u++) acc[u] = make_float4(0.f, 0.f, 0.f, 0.f);

    LOADW(0)
    STOREW()
    __syncthreads();

    const float* lrow = Wls + lane * 4;     // + idx*256 floats selects the row

    for (int kc = 0; kc < nkc; kc++) {
        if (kc + 1 < nkc) LOADW(kc + 1)     // overlaps the index loops below
        const uint32_t* c32 =
            (const uint32_t*)(cnt8 + ((size_t)kc * 64 + b) * 320 + t0);
        const uint4* pb = (const uint4*)(pk32 + ((size_t)kc * 64 + b) * 300 * 8);
#pragma unroll
        for (int up = 0; up < RPW / 2; up++) {
            const int u0 = up * 2, u1 = up * 2 + 1;
            const int ts0 = t0 + u0 * 4 + wvs;
            const int ts1 = t0 + u1 * 4 + wvs;
            const int s0 = (ts0 < 299) ? ts0 : 299;   // clamp tail (guarded)
            const int s1 = (ts1 < 299) ? ts1 : 299;
            int ng0 = (int)((c32[u0] >> (wvs * 8)) & 0xffu);
            int ng1 = (int)((c32[u1] >> (wvs * 8)) & 0xffu);
            if (ts0 >= 300) ng0 = 0;
            if (ts1 >= 300) ng1 = 0;
            const uint4 A0 = pb[(size_t)s0 * 2];
            const uint4 A1 = pb[(size_t)s0 * 2 + 1];
            const uint4 B0 = pb[(size_t)s1 * 2];
            const uint4 B1 = pb[(size_t)s1 * 2 + 1];
            const int ngm = (ng0 > ng1) ? ng0 : ng1;
            float4 a0 = acc[u0];
            float4 a1 = acc[u1];
            GRP2(0, A0.x, B0.x) GRP2(1, A0.y, B0.y)
            GRP2(2, A0.z, B0.z) GRP2(3, A0.w, B0.w)
            GRP2(4, A1.x, B1.x) GRP2(5, A1.y, B1.y)
            GRP2(6, A1.z, B1.z) GRP2(7, A1.w, B1.w)
            acc[u0] = a0;
            acc[u1] = a1;
        }
        if (kc + 1 < nkc) {
            __syncthreads();
            STOREW()
            __syncthreads();
        }
    }

    float* Cb = C + (size_t)b * 300 * O;
#pragma unroll
    for (int u = 0; u < RPW; u++) {
        const int t = t0 + u * 4 + wvs;
        const int o = oc + lane * 4;
        if (t < 300 && o + 3 < O)           // O%4==0 -> all-or-nothing
            *reinterpret_cast<float4*>(&Cb[(size_t)t * O + o]) = acc[u];
    }
}

// ---------------------------------------------------------------------------
// LIF in time-major layout, in-place: C[b,t,o] currents -> spikes.
// One thread per (b,o); strided column walk, 8-deep unrolled prefetch ring.
// ---------------------------------------------------------------------------
#define LIF_STEP_S(xval, sval)                                                 \
    {                                                                          \
        const float y = A1 * y1 + A2 * y2 + Bc * (xval); y2 = y1; y1 = y;      \
        const float v = y + bi + r;                                            \
        sval = (v >= 1.0f) ? 1.0f : 0.0f;                                      \
        r = r * EMF - sval;                                                    \
    }

__global__ __launch_bounds__(64) void lif_t(
    float* __restrict__ C, const float* __restrict__ bias,
    const float* __restrict__ a1p, const float* __restrict__ a2p,
    const float* __restrict__ bp, int O)
{
    const int o = blockIdx.x * 64 + threadIdx.x;
    const int b = blockIdx.y;
    if (o >= O) return;
    const float A1 = a1p[0], A2 = a2p[0], Bc = bp[0];
    const float bi = bias[o];
    float* col = C + (size_t)b * 300 * O + o;

    float pf[8];
#pragma unroll
    for (int u = 0; u < 8; u++) pf[u] = col[(size_t)u * O];

    float y1 = 0.f, y2 = 0.f, r = 0.f;
    for (int blk = 0; blk < 37; blk++) {       // t = 0..295
#pragma unroll
        for (int u = 0; u < 8; u++) {
            const int t = blk * 8 + u;
            const float x = pf[u];
            if (t + 8 < 300) pf[u] = col[(size_t)(t + 8) * O];
            float s;
            LIF_STEP_S(x, s)
            col[(size_t)t * O] = s;
        }
    }
#pragma unroll
    for (int u = 0; u < 4; u++) {              // t = 296..299
        const float x = pf[u];
        float s;
        LIF_STEP_S(x, s)
        col[(size_t)(296 + u) * O] = s;
    }
}

// ---------------------------------------------------------------------------
// Layer-4 LIF + fixed output dual-exp IIR. C: currents->spikes (in place),
// F: filtered output. Both [B,T,O], O=300.
// ---------------------------------------------------------------------------
__global__ __launch_bounds__(64) void lif4_t(
    float* __restrict__ C, float* __restrict__ F,
    const float* __restrict__ bias,
    const float* __restrict__ a1p, const float* __restrict__ a2p,
    const float* __restrict__ bp, int O)
{
    const int o = blockIdx.x * 64 + threadIdx.x;
    const int b = blockIdx.y;
    if (o >= O) return;
    const float A1 = a1p[0], A2 = a2p[0], Bc = bp[0];
    const float bi = bias[o];
    float* col  = C + (size_t)b * 300 * O + o;
    float* fcol = F + (size_t)b * 300 * O + o;

    float pf[8];
#pragma unroll
    for (int u = 0; u < 8; u++) pf[u] = col[(size_t)u * O];

    float y1 = 0.f, y2 = 0.f, r = 0.f;
    float z1 = 0.f, z2 = 0.f;
    for (int blk = 0; blk < 37; blk++) {
#pragma unroll
        for (int u = 0; u < 8; u++) {
            const int t = blk * 8 + u;
            const float x = pf[u];
            if (t + 8 < 300) pf[u] = col[(size_t)(t + 8) * O];
            float s;
            LIF_STEP_S(x, s)
            const float z = A1C * z1 + A2C * z2 + BC * s; z2 = z1; z1 = z;
            col[(size_t)t * O]  = s;
            fcol[(size_t)t * O] = z;
        }
    }
#pragma unroll
    for (int u = 0; u < 4; u++) {
        const int t = 296 + u;
        const float x = pf[u];
        float s;
        LIF_STEP_S(x, s)
        const float z = A1C * z1 + A2C * z2 + BC * s; z2 = z1; z1 = z;
        col[(size_t)t * O]  = s;
        fcol[(size_t)t * O] = z;
    }
}

// ---------------------------------------------------------------------------
extern "C" void kernel_launch(void* const* d_in, const int* in_sizes, int n_in,
                              void* d_out, int out_size, void* d_ws, size_t ws_size,
                              hipStream_t stream)
{
    const float* inputs = (const float*)d_in[0];           // [64,300,300] binary
    const float* a1_1 = (const float*)d_in[1];
    const float* a2_1 = (const float*)d_in[2];
    const float* b_1  = (const float*)d_in[3];
    const float* W1   = (const float*)d_in[4];             // [500,300]
    const float* bias1= (const float*)d_in[5];
    const float* a1_2 = (const float*)d_in[6];
    const float* a2_2 = (const float*)d_in[7];
    const float* b_2  = (const float*)d_in[8];
    const float* W2   = (const float*)d_in[9];             // [200,500]
    const float* bias2= (const float*)d_in[10];
    const float* a1_3 = (const float*)d_in[11];
    const float* a2_3 = (const float*)d_in[12];
    const float* b_3  = (const float*)d_in[13];
    const float* W3   = (const float*)d_in[14];            // [500,200]
    const float* bias3= (const float*)d_in[15];
    const float* a1_4 = (const float*)d_in[16];
    const float* a2_4 = (const float*)d_in[17];
    const float* b_4  = (const float*)d_in[18];
    const float* W4   = (const float*)d_in[19];            // [300,500]
    const float* bias4= (const float*)d_in[20];

    const int B = 64;

    // Workspace (53.76 MB): c1 = 9.6M floats, c2 = 3.84M floats.
    float* ws = (float*)d_ws;
    float* c1 = ws;                 // [B,T,500]; later filt_tmp [B,T,300]
    float* c2 = ws + 9600000;       // [B,T,200]

    // d_out regions double as scratch until the final transposes:
    // reg1 [0..5.76M): Wt1..4 (500K fl) + idx scratch, later final s4 [B,O,T]
    // reg2 [5.76M..11.52M): inputT / c4 / s4_tmp [B,T,300], later final filt
    float* out = (float*)d_out;
    float* reg1 = out;
    float* reg2 = out + 5760000;
    float* Wt1 = reg1;              // [300,500] = 150000
    float* Wt2 = reg1 + 150000;     // [500,200] = 100000
    float* Wt3 = reg1 + 250000;     // [200,500] = 100000
    float* Wt4 = reg1 + 350000;     // [500,300] = 150000
    uint8_t*  cnt8 = (uint8_t*)(reg1 + 500000);   // 16*64*320 B = 328 KB
    uint32_t* pk32 = (uint32_t*)(reg1 + 582000);  // 16*64*300*8 u32 = 9.8 MB
                                                  // ends at reg1+3,039,600

    const dim3 tb(32, 8);

    // Weight transposes W[O,K] -> Wt[K,O]
    transpose_rc<<<dim3(10, 16, 1), tb, 0, stream>>>(W1, Wt1, 500, 300);
    transpose_rc<<<dim3(16,  7, 1), tb, 0, stream>>>(W2, Wt2, 200, 500);
    transpose_rc<<<dim3( 7, 16, 1), tb, 0, stream>>>(W3, Wt3, 500, 200);
    transpose_rc<<<dim3(16, 10, 1), tb, 0, stream>>>(W4, Wt4, 300, 500);
    // Input spikes [B,IN,T] -> [B,T,IN]
    transpose_rc<<<dim3(10, 10, B), tb, 0, stream>>>(inputs, reg2, 300, 300);

    // Layer 1: 300 -> 500  (nkc = 10)
    build_idx<<<dim3(75, B), 256, 0, stream>>>(reg2, cnt8, pk32, 300, 10);
    spmm_idx<8><<<dim3(2, 10, B), 256, 0, stream>>>(Wt1, c1, cnt8, pk32, 300, 500, 10);
    lif_t<<<dim3(8, B), 64, 0, stream>>>(c1, bias1, a1_1, a2_1, b_1, 500);
    // Layer 2: 500 -> 200  (nkc = 16; 1 o-chunk -> RPW=4 for more blocks)
    build_idx<<<dim3(75, B), 256, 0, stream>>>(c1, cnt8, pk32, 500, 16);
    spmm_idx<4><<<dim3(1, 19, B), 256, 0, stream>>>(Wt2, c2, cnt8, pk32, 500, 200, 16);
    lif_t<<<dim3(4, B), 64, 0, stream>>>(c2, bias2, a1_2, a2_2, b_2, 200);
    // Layer 3: 200 -> 500  (nkc = 7)
    build_idx<<<dim3(75, B), 256, 0, stream>>>(c2, cnt8, pk32, 200, 7);
    spmm_idx<8><<<dim3(2, 10, B), 256, 0, stream>>>(Wt3, c1, cnt8, pk32, 200, 500, 7);
    lif_t<<<dim3(8, B), 64, 0, stream>>>(c1, bias3, a1_3, a2_3, b_3, 500);
    // Layer 4: 500 -> 300 into reg2 (inputT dead); fused LIF + output filter
    build_idx<<<dim3(75, B), 256, 0, stream>>>(c1, cnt8, pk32, 500, 16);
    spmm_idx<8><<<dim3(2, 10, B), 256, 0, stream>>>(Wt4, reg2, cnt8, pk32, 500, 300, 16);
    lif4_t<<<dim3(5, B), 64, 0, stream>>>(reg2, c1, bias4, a1_4, a2_4, b_4, 300);

    // Final transposes [B,T,O] -> [B,O,T]: s4 (overwrites Wt/idx), then filt.
    transpose_rc<<<dim3(10, 10, B), tb, 0, stream>>>(reg2, reg1, 300, 300);
    transpose_rc<<<dim3(10, 10, B), tb, 0, stream>>>(c1, reg2, 300, 300);
}